// Round 1
// baseline (4665.170 us; speedup 1.0000x reference)
//
#include <hip/hip_runtime.h>

// LGA3: 3 chained local-guided-aggregation passes.
// cost [B=2, D=64, H=384, W=768] fp32, weights [B, 75, H, W] fp32 (3 groups x 25 taps).
// out[b,d,h,w] = sum_{i,j in 5x5} w0[ij]*c[d-1,h+i-2,w+j-2] + w1[ij]*c[d,...] + w2[ij]*c[d+1,...]
// (zero-padded in d by 1, in h/w by 2).

#define B_ 2
#define D_ 64
#define H_ 384
#define W_ 768
static constexpr int HW = H_ * W_;
static constexpr int DPT = 8;    // disparities per thread
static constexpr int WT  = 64;   // w-chunk per block

__global__ __launch_bounds__(512) void lga_pass(const float* __restrict__ src,
                                                const float* __restrict__ wts,
                                                float* __restrict__ dst) {
  const int tx = threadIdx.x;               // 0..63  (w within chunk)
  const int ty = threadIdx.y;               // 0..7   (d-group)
  const int w  = blockIdx.x * WT + tx;
  const int h  = blockIdx.y;
  const int b  = blockIdx.z;
  const int d0 = ty * DPT;

  // weight base for this (b,h,w): channel c is at wb[c*HW]
  const float* wb = wts + (size_t)b * 75 * HW + (size_t)h * W_ + w;
  // source plane base for this b
  const float* sb = src + (size_t)b * D_ * HW;

  float acc[DPT];
#pragma unroll
  for (int k = 0; k < DPT; ++k) acc[k] = 0.f;

#pragma unroll
  for (int i = 0; i < 5; ++i) {
    const int h_in = h + i - 2;
    const bool hv = (unsigned)h_in < (unsigned)H_;
#pragma unroll
    for (int j = 0; j < 5; ++j) {
      const int w_in = w + j - 2;
      const bool sv = hv && ((unsigned)w_in < (unsigned)W_);
      const int tap = i * 5 + j;
      const float w0 = wb[(size_t)(0 * 25 + tap) * HW];
      const float w1 = wb[(size_t)(1 * 25 + tap) * HW];
      const float w2 = wb[(size_t)(2 * 25 + tap) * HW];

      // planes d0-1 .. d0+DPT  (DPT+2 values), zero outside [0,D)
      const ptrdiff_t sp_off = (ptrdiff_t)h_in * W_ + w_in;
      float val[DPT + 2];
#pragma unroll
      for (int k = 0; k < DPT + 2; ++k) {
        const int dd = d0 - 1 + k;
        const bool dv = sv && (dd >= 0) && (dd < D_);
        val[k] = dv ? sb[(ptrdiff_t)dd * HW + sp_off] : 0.f;
      }
#pragma unroll
      for (int k = 0; k < DPT; ++k)
        acc[k] = fmaf(w0, val[k], fmaf(w1, val[k + 1], fmaf(w2, val[k + 2], acc[k])));
    }
  }

  float* dp = dst + (((size_t)b * D_ + d0) * H_ + h) * W_ + w;
#pragma unroll
  for (int k = 0; k < DPT; ++k) dp[(size_t)k * HW] = acc[k];
}

extern "C" void kernel_launch(void* const* d_in, const int* in_sizes, int n_in,
                              void* d_out, int out_size, void* d_ws, size_t ws_size,
                              hipStream_t stream) {
  const float* cost = (const float*)d_in[0];
  const float* wts  = (const float*)d_in[1];
  float* out = (float*)d_out;
  float* ws  = (float*)d_ws;

  dim3 grid(W_ / WT, H_, B_);
  dim3 block(WT, D_ / DPT);   // 64 x 8 = 512 threads

  // pass 1: input -> out ; pass 2: out -> ws ; pass 3: ws -> out
  lga_pass<<<grid, block, 0, stream>>>(cost, wts, out);
  lga_pass<<<grid, block, 0, stream>>>(out, wts, ws);
  lga_pass<<<grid, block, 0, stream>>>(ws, wts, out);
}

// Round 2
// 1409.937 us; speedup vs baseline: 3.3088x; 3.3088x over previous
//
#include <hip/hip_runtime.h>

// LGA3: 3 chained local-guided-aggregation passes.
// cost [B=2, D=64, H=384, W=768] fp32, weights [B, 75, H, W] fp32 (3 groups x 25 taps).
// out[b,d,h,w] = sum_{i,j in 5x5} w0[ij]*c[d-1,h+i-2,w+j-2] + w1[ij]*c[d,...] + w2[ij]*c[d+1,...]

#define B_ 2
#define D_ 64
#define H_ 384
#define W_ 768
static constexpr int HW = H_ * W_;
static constexpr int DPT  = 16;       // disparities per thread
static constexpr int NTY  = D_ / DPT; // 4 -> 256 threads/block
static constexpr int WT   = 64;       // w-chunk per block
static constexpr int HSEG = 8;        // h rows streamed per block (intra-block L2 reuse)

__global__ __launch_bounds__(256, 4) void lga_pass(const float* __restrict__ src,
                                                   const float* __restrict__ wts,
                                                   float* __restrict__ dst) {
  const int tx = threadIdx.x;             // 0..63 (w)
  const int ty = threadIdx.y;             // 0..3  (d-group)
  const int w  = blockIdx.x * WT + tx;
  const int hs = blockIdx.y * HSEG;
  const int b  = blockIdx.z;
  const int d0 = ty * DPT;

  const float* sb    = src + (size_t)b * D_ * HW;
  const float* wbase = wts + (size_t)b * 75 * HW + w;

  const bool has_lo = (d0 > 0);           // plane d0-1 exists
  const bool has_hi = (d0 + DPT < D_);    // plane d0+DPT exists

  // clamped column offsets + validity, hoisted out of everything
  int  wofs[5];
  bool wok[5];
#pragma unroll
  for (int j = 0; j < 5; ++j) {
    const int wi = w + j - 2;
    wok[j]  = (unsigned)wi < (unsigned)W_;
    wofs[j] = wi < 0 ? 0 : (wi >= W_ ? W_ - 1 : wi);
  }

#pragma unroll 1
  for (int h = hs; h < hs + HSEG; ++h) {
    float acc[DPT];
#pragma unroll
    for (int k = 0; k < DPT; ++k) acc[k] = 0.f;

    const float* wrow = wbase + (size_t)h * W_;

#pragma unroll 1
    for (int i = 0; i < 5; ++i) {
      const int h_in = h + i - 2;
      if ((unsigned)h_in >= (unsigned)H_) continue;   // wave-uniform skip

      // 15 weights for this tap row; zero the w-invalid columns
      float w0[5], w1[5], w2[5];
#pragma unroll
      for (int j = 0; j < 5; ++j) {
        const int tap = i * 5 + j;
        const float a0 = wrow[(size_t)(tap)      * HW];
        const float a1 = wrow[(size_t)(tap + 25) * HW];
        const float a2 = wrow[(size_t)(tap + 50) * HW];
        w0[j] = wok[j] ? a0 : 0.f;
        w1[j] = wok[j] ? a1 : 0.f;
        w2[j] = wok[j] ? a2 : 0.f;
      }

      const float* srow = sb + (size_t)h_in * W_;

      // planes m = 0..DPT+1 <-> d = d0-1+m ; val[m] feeds acc[m](w0), acc[m-1](w1), acc[m-2](w2)
#pragma unroll
      for (int m = 0; m < DPT + 2; ++m) {
        const bool pv = (m == 0) ? has_lo : ((m == DPT + 1) ? has_hi : true);
        if (pv) {                                     // wave-uniform (d0 uniform per wave)
          const float* p = srow + (ptrdiff_t)(d0 - 1 + m) * HW;
          float v[5];
#pragma unroll
          for (int j = 0; j < 5; ++j) v[j] = p[wofs[j]];
#pragma unroll
          for (int j = 0; j < 5; ++j) {
            if (m < DPT)                acc[m]     = fmaf(w0[j], v[j], acc[m]);
            if (m >= 1 && m - 1 < DPT)  acc[m - 1] = fmaf(w1[j], v[j], acc[m - 1]);
            if (m >= 2)                 acc[m - 2] = fmaf(w2[j], v[j], acc[m - 2]);
          }
        }
      }
    }

    float* dp = dst + (((size_t)b * D_ + d0) * H_ + h) * W_ + w;
#pragma unroll
    for (int k = 0; k < DPT; ++k) dp[(size_t)k * HW] = acc[k];
  }
}

extern "C" void kernel_launch(void* const* d_in, const int* in_sizes, int n_in,
                              void* d_out, int out_size, void* d_ws, size_t ws_size,
                              hipStream_t stream) {
  const float* cost = (const float*)d_in[0];
  const float* wts  = (const float*)d_in[1];
  float* out = (float*)d_out;
  float* ws  = (float*)d_ws;

  dim3 grid(W_ / WT, H_ / HSEG, B_);   // 12 x 48 x 2 = 1152 blocks
  dim3 block(WT, NTY);                 // 64 x 4 = 256 threads

  lga_pass<<<grid, block, 0, stream>>>(cost, wts, out);
  lga_pass<<<grid, block, 0, stream>>>(out, wts, ws);
  lga_pass<<<grid, block, 0, stream>>>(ws, wts, out);
}

// Round 3
// 1252.282 us; speedup vs baseline: 3.7253x; 1.1259x over previous
//
#include <hip/hip_runtime.h>

// LGA3: 3 chained local-guided-aggregation passes, rolling-accumulator stencil.
// cost [B=2, D=64, H=384, W=768] fp32, weights [B, 75, H, W] fp32 (3 groups x 25 taps).
// out[b,d,h,w] = sum_{i,j in 5x5} w0[ij]*c[d-1,h+i-2,w+j-2] + w1[ij]*c[d,...] + w2[ij]*c[d+1,...]
//
// Each block: 64-wide w chunk x all 64 d x HSEG output rows. Input rows are
// streamed ONCE; each input row feeds the 5 output rows that window it
// (5 rolling register accumulator slots, rotated with static indices).
// Slot s at iteration r holds output row o = hs + (r-4) + s and uses tap row
// i = 4 - s. Slot 0 completes at end of iteration r and is written out.

#define B_ 2
#define D_ 64
#define H_ 384
#define W_ 768
static constexpr int HW  = H_ * W_;
static constexpr int DPT = 8;         // disparities per thread
static constexpr int NTY = D_ / DPT;  // 8 -> 512 threads
static constexpr int WT  = 64;
static constexpr int HSEG = 8;        // output rows per block

__global__ __launch_bounds__(512, 4) void lga_pass(const float* __restrict__ src,
                                                   const float* __restrict__ wts,
                                                   float* __restrict__ dst) {
  const int tx = threadIdx.x;              // 0..63 (w)
  const int ty = threadIdx.y;              // 0..7  (d-group) -- wave-uniform
  const int w  = blockIdx.x * WT + tx;
  const int hs = blockIdx.y * HSEG;
  const int b  = blockIdx.z;
  const int d0 = ty * DPT;

  const float* sb = src + (size_t)b * D_ * HW;
  const float* wb = wts + (size_t)b * 75 * HW + w;

  const bool has_lo = (d0 > 0);
  const bool has_hi = (d0 + DPT < D_);
  // clamped plane offsets so speculated loads stay in-bounds
  const ptrdiff_t lo_off = has_lo ? -(ptrdiff_t)HW : 0;
  const ptrdiff_t hi_off = has_hi ? (ptrdiff_t)DPT * HW : 0;

  // clamped column offsets + validity (w edges -> zero value, matches padding)
  int  wofs[5];
  bool wok[5];
#pragma unroll
  for (int j = 0; j < 5; ++j) {
    const int wi = w + j - 2;
    wok[j]  = (unsigned)wi < (unsigned)W_;
    wofs[j] = wi < 0 ? 0 : (wi >= W_ ? W_ - 1 : wi);
  }

  float acc[5][DPT];
#pragma unroll
  for (int s = 0; s < 5; ++s)
#pragma unroll
    for (int k = 0; k < DPT; ++k) acc[s][k] = 0.f;

#pragma unroll 1
  for (int r = 0; r < HSEG + 4; ++r) {
    const int h_in = hs - 2 + r;

    if ((unsigned)h_in < (unsigned)H_) {              // wave-uniform
      const float* srow = sb + (size_t)h_in * W_ + (ptrdiff_t)d0 * HW;

#pragma unroll
      for (int j = 0; j < 5; ++j) {
        const float* p = srow + wofs[j];
        float v[DPT + 2];
        v[0] = (has_lo && wok[j]) ? p[lo_off] : 0.f;
#pragma unroll
        for (int m = 1; m <= DPT; ++m)
          v[m] = wok[j] ? p[(ptrdiff_t)(m - 1) * HW] : 0.f;
        v[DPT + 1] = (has_hi && wok[j]) ? p[hi_off] : 0.f;

#pragma unroll
        for (int s = 0; s < 5; ++s) {
          if ((unsigned)(r - 4 + s) < (unsigned)HSEG) {   // uniform slot validity
            const int o   = hs + r - 4 + s;               // output row in [hs, hs+HSEG)
            const int tap = (4 - s) * 5 + j;
            const float* wr = wb + (size_t)o * W_;
            const float w0 = wr[(size_t)tap * HW];
            const float w1 = wr[(size_t)(tap + 25) * HW];
            const float w2 = wr[(size_t)(tap + 50) * HW];
#pragma unroll
            for (int k = 0; k < DPT; ++k)
              acc[s][k] = fmaf(w0, v[k],
                          fmaf(w1, v[k + 1],
                          fmaf(w2, v[k + 2], acc[s][k])));
          }
        }
      }
    }

    // slot 0 holds output row hs + r - 4, complete after this iteration
    if (r >= 4) {
      const int o = hs + r - 4;
      float* dp = dst + (((size_t)b * D_ + d0) * H_ + o) * W_ + w;
#pragma unroll
      for (int k = 0; k < DPT; ++k) dp[(size_t)k * HW] = acc[0][k];
    }

    // rotate accumulator slots (static indices -> stays in registers)
#pragma unroll
    for (int s = 0; s < 4; ++s)
#pragma unroll
      for (int k = 0; k < DPT; ++k) acc[s][k] = acc[s + 1][k];
#pragma unroll
    for (int k = 0; k < DPT; ++k) acc[4][k] = 0.f;
  }
}

extern "C" void kernel_launch(void* const* d_in, const int* in_sizes, int n_in,
                              void* d_out, int out_size, void* d_ws, size_t ws_size,
                              hipStream_t stream) {
  const float* cost = (const float*)d_in[0];
  const float* wts  = (const float*)d_in[1];
  float* out = (float*)d_out;
  float* ws  = (float*)d_ws;

  dim3 grid(W_ / WT, H_ / HSEG, B_);   // 12 x 48 x 2 = 1152 blocks
  dim3 block(WT, NTY);                 // 64 x 8 = 512 threads

  lga_pass<<<grid, block, 0, stream>>>(cost, wts, out);
  lga_pass<<<grid, block, 0, stream>>>(out, wts, ws);
  lga_pass<<<grid, block, 0, stream>>>(ws, wts, out);
}

// Round 4
// 835.376 us; speedup vs baseline: 5.5845x; 1.4991x over previous
//
#include <hip/hip_runtime.h>

// LGA3: 3 chained local-guided-aggregation passes, rolling-accumulator stencil
// with LDS-staged cost planes (double-buffered global_load_lds pipeline).
// cost [B=2, D=64, H=384, W=768] fp32, weights [B, 75, H, W] fp32.
// out[b,d,h,w] = sum_{i,j in 5x5} w0*c[d-1,h+i-2,w+j-2] + w1*c[d,..] + w2*c[d+1,..]
//
// Block: 64-wide w chunk x all 64 d x HSEG=8 output rows; 512 thr (8 waves, wave=ty).
// Per input row r: LDS tile = 66 planes x 72 floats (row 0 / row 65 permanently zero
// for the d=-1 / d=64 pads; cols hold w0-4 .. w0+67, w-edge cols zeroed in LDS).
// Stage of row r+1 (18 x global_load_lds dwordx4 chunks) overlaps compute of row r.

#define B_ 2
#define D_ 64
#define H_ 384
#define W_ 768
static constexpr int HW    = H_ * W_;
static constexpr int DPT   = 8;          // disparities per thread
static constexpr int NTY   = D_ / DPT;   // 8 waves
static constexpr int WT    = 64;
static constexpr int HSEG  = 8;          // output rows per block
static constexpr int RITER = HSEG + 4;   // 12 streamed input rows
static constexpr int LROW  = 72;         // floats per LDS plane row (288 B = 18 granules)
static constexpr int LPL   = 66;         // plane rows: 0 = zero(d=-1), 1..64 = d, 65 = zero(d=64)
static constexpr int NCHUNK = 18;        // 1 KiB wave-chunks per row stage (64*288/1024)

__device__ __forceinline__ void gld_lds16(const float* g, float* l) {
  __builtin_amdgcn_global_load_lds((const __attribute__((address_space(1))) unsigned int*)g,
                                   (__attribute__((address_space(3))) unsigned int*)l,
                                   16, 0, 0);
}

__global__ __launch_bounds__(512, 4) void lga_pass(const float* __restrict__ src,
                                                   const float* __restrict__ wts,
                                                   float* __restrict__ dst) {
  __shared__ float lds[2][LPL * LROW];

  const int tx = threadIdx.x;            // 0..63 = lane (wave = ty)
  const int ty = threadIdx.y;            // 0..7
  const int bx = blockIdx.x;
  const int w0 = bx * WT, w = w0 + tx;
  const int hs = blockIdx.y * HSEG;
  const int b  = blockIdx.z;
  const int d0 = ty * DPT;

  const float* sb = src + (size_t)b * D_ * HW;
  const float* wb = wts + (size_t)b * 75 * HW + w;

  // ---- one-time zeroing of the d-pad planes (rows 0 and 65 of both buffers)
  {
    const int flat = ty * WT + tx;                 // 0..511
    if (flat < 2 * 2 * LROW) {                     // 288 entries
      const int q   = flat / (2 * LROW);
      const int rem = flat - q * (2 * LROW);
      const int row = (rem >= LROW) ? (LPL - 1) : 0;
      const int col = (rem >= LROW) ? rem - LROW : rem;
      lds[q][row * LROW + col] = 0.f;
    }
  }

  // ---- async stage of one input row into buffer `buf`
  auto stage = [&](int buf, int h_in) {
#pragma unroll
    for (int q = 0; q < 3; ++q) {
      const int c = ty + q * 8;                    // chunk id, wave-uniform
      if (c < NCHUNK) {
        const int G = c * 64 + tx;                 // granule 0..1151
        const int d = G / NCHUNK;                  // source plane 0..63
        const int k = G - d * NCHUNK;              // 16B granule within row
        long idx = (long)d * HW + (long)h_in * W_ + (w0 - 4) + (k << 2);
        idx = idx < 0 ? 0 : idx;                   // clamp (garbage cols zeroed/unread)
        const long mx = (long)D_ * HW - 4;
        idx = idx > mx ? mx : idx;
        gld_lds16(sb + idx, &lds[buf][LROW + c * 256]);  // dst rows 1..64, wave-uniform base
      }
    }
  };

  // prologue: stage row 0 into buf 0
  {
    const int h_in = hs - 2;
    if (h_in >= 0) stage(0, h_in);
  }
  __syncthreads();

  float acc[5][DPT];
#pragma unroll
  for (int s = 0; s < 5; ++s)
#pragma unroll
    for (int k = 0; k < DPT; ++k) acc[s][k] = 0.f;

  int n = 0;
#pragma unroll 1
  for (int r = 0; r < RITER; ++r) {
    // issue stage of next row into the other buffer (overlaps compute below)
    const int h_nx = hs - 2 + r + 1;
    if (r + 1 < RITER && (unsigned)h_nx < (unsigned)H_) stage(n ^ 1, h_nx);

    const int h_in = hs - 2 + r;
    if ((unsigned)h_in < (unsigned)H_) {           // wave-uniform row validity
      float* cur = lds[n];

      // w-edge zero padding: each wave zeroes the halo cols of its own planes
      if (bx == 0 && tx < 20)
        cur[(d0 + (tx >> 1)) * LROW + 2 + (tx & 1)] = 0.f;
      if (bx == (W_ / WT - 1) && tx < 20)
        cur[(d0 + (tx >> 1)) * LROW + 68 + (tx & 1)] = 0.f;

      // LDS -> regs: vv[j][m] = cost[d0-1+m, h_in, w+j-2]  (plane row d0+m)
      float vv[5][DPT + 2];
#pragma unroll
      for (int j = 0; j < 5; ++j)
#pragma unroll
        for (int m = 0; m < DPT + 2; ++m)
          vv[j][m] = cur[(d0 + m) * LROW + tx + j + 2];

      // 5 rolling slots: slot s -> output row hs+r-4+s, tap row 4-s
#pragma unroll
      for (int s = 0; s < 5; ++s) {
        if ((unsigned)(r - 4 + s) < (unsigned)HSEG) {
          const int o     = hs + r - 4 + s;
          const int ibase = (4 - s) * 5;
          const float* wr = wb + (size_t)o * W_;
#pragma unroll
          for (int j = 0; j < 5; ++j) {
            const float w0v = wr[(size_t)(ibase + j) * HW];
            const float w1v = wr[(size_t)(ibase + j + 25) * HW];
            const float w2v = wr[(size_t)(ibase + j + 50) * HW];
#pragma unroll
            for (int k = 0; k < DPT; ++k)
              acc[s][k] = fmaf(w0v, vv[j][k],
                          fmaf(w1v, vv[j][k + 1],
                          fmaf(w2v, vv[j][k + 2], acc[s][k])));
          }
        }
      }
    }

    // slot 0 complete -> write output row hs+r-4
    if (r >= 4) {
      const int o = hs + r - 4;
      float* dp = dst + (((size_t)b * D_ + d0) * H_ + o) * W_ + w;
#pragma unroll
      for (int k = 0; k < DPT; ++k) dp[(size_t)k * HW] = acc[0][k];
    }

    // rotate slots (static indices)
#pragma unroll
    for (int s = 0; s < 4; ++s)
#pragma unroll
      for (int k = 0; k < DPT; ++k) acc[s][k] = acc[s + 1][k];
#pragma unroll
    for (int k = 0; k < DPT; ++k) acc[4][k] = 0.f;

    __syncthreads();   // drains global_load_lds (vmcnt) + joins waves; buffers swap
    n ^= 1;
  }
}

extern "C" void kernel_launch(void* const* d_in, const int* in_sizes, int n_in,
                              void* d_out, int out_size, void* d_ws, size_t ws_size,
                              hipStream_t stream) {
  const float* cost = (const float*)d_in[0];
  const float* wts  = (const float*)d_in[1];
  float* out = (float*)d_out;
  float* ws  = (float*)d_ws;

  dim3 grid(W_ / WT, H_ / HSEG, B_);   // 12 x 48 x 2 = 1152 blocks
  dim3 block(WT, NTY);                 // 64 x 8 = 512 threads

  lga_pass<<<grid, block, 0, stream>>>(cost, wts, out);
  lga_pass<<<grid, block, 0, stream>>>(out, wts, ws);
  lga_pass<<<grid, block, 0, stream>>>(ws, wts, out);
}